// Round 7
// baseline (1975.043 us; speedup 1.0000x reference)
//
#include <hip/hip_runtime.h>

#define NN 2048
#define NE 32768
#define DF 2048
#define TOPK 20
#define RMAXF 1e-5f

typedef __attribute__((ext_vector_type(4))) float f32x4;

// ---------------- zero counts/cursor ----------------
__global__ __launch_bounds__(256) void zero_kernel(int* __restrict__ counts, int* __restrict__ cursor) {
    int idx = blockIdx.x * 256 + threadIdx.x;
    if (idx < NN) { counts[idx] = 0; cursor[idx] = 0; }
}

// ---------------- per-row edge counts (duplicates kept) ----------------
__global__ __launch_bounds__(256) void count_kernel(const int* __restrict__ ei, int* __restrict__ counts) {
    int e = blockIdx.x * 256 + threadIdx.x;
    if (e < NE) atomicAdd(&counts[ei[e]], 1);
}

// ---------------- exclusive scan -> rowptr; winv05 = 0.5/deg ----------------
__global__ __launch_bounds__(256) void scan_kernel(const int* __restrict__ counts, int* __restrict__ rowptr,
                                                   float* __restrict__ winv05) {
    __shared__ int part[256];
    int tid = threadIdx.x;
    int base = tid * 8;
    int loc[8];
    int s = 0;
#pragma unroll
    for (int l = 0; l < 8; ++l) { loc[l] = s; s += counts[base + l]; }
    part[tid] = s;
    __syncthreads();
    for (int off = 1; off < 256; off <<= 1) {
        int v = (tid >= off) ? part[tid - off] : 0;
        __syncthreads();
        part[tid] += v;
        __syncthreads();
    }
    int excl = part[tid] - s;
#pragma unroll
    for (int l = 0; l < 8; ++l) {
        rowptr[base + l] = excl + loc[l];
        int c = counts[base + l];
        winv05[base + l] = c ? 0.5f / (float)c : 0.0f;
    }
    if (tid == 255) rowptr[NN] = excl + s;
}

// ---------------- fill packed CSR edges: pedges[k] = (src<<11)|dst (src ascending) ----------------
__global__ __launch_bounds__(256) void fill_kernel(const int* __restrict__ ei, const int* __restrict__ rowptr,
                                                   int* __restrict__ cursor, int* __restrict__ pedges) {
    int e = blockIdx.x * 256 + threadIdx.x;
    if (e < NE) {
        int r = ei[e];
        int c = ei[NE + e];
        int pos = atomicAdd(&cursor[r], 1);
        pedges[rowptr[r] + pos] = (r << 11) | c;
    }
}

// ---------------- per-source-row local push + top-20, all in LDS ----------------
// R5's proven skeleton (explicit R/D/P, per-round D reset, barrier-separated flag)
// + R6's coalesced packed-edge sweep (no dependent per-edge global loads).
__global__ __launch_bounds__(256) void push_topk_kernel(const int* __restrict__ pedges,
                                                        const float* __restrict__ gwinv,
                                                        float* __restrict__ tkv, int* __restrict__ tki) {
    __shared__ float R[NN];
    __shared__ float D[NN];       // incoming spread; reused as cv/ci scratch for topk
    __shared__ float P[NN];
    __shared__ float pamt[NN];    // per-source scatter amount this round (0 if not pushing)
    __shared__ int groupAct[32];  // 1 if any source in group of 64 pushes this round
    __shared__ unsigned char chunkLo[128], chunkHi[128];  // source-group span of each 256-edge chunk
    __shared__ int sflag;

    int tid = threadIdx.x, row = blockIdx.x;
    int base = tid * 8;
    const f32x4 z4 = (f32x4){0.f, 0.f, 0.f, 0.f};
    *(f32x4*)&R[base] = z4; *(f32x4*)&R[base + 4] = z4;
    *(f32x4*)&D[base] = z4; *(f32x4*)&D[base + 4] = z4;
    *(f32x4*)&P[base] = z4; *(f32x4*)&P[base + 4] = z4;
    if ((row >> 3) == tid) R[row] = 1.0f;  // owner thread: program-order after its own zeroing
    if (tid < 32) groupAct[tid] = 0;
    if (tid < 128) {
        // chunk c covers edges [c*256, c*256+256); CSR order -> sources ascending
        chunkLo[tid] = (unsigned char)(pedges[tid * 256] >> 17);        // src>>6
        chunkHi[tid] = (unsigned char)(pedges[tid * 256 + 255] >> 17);
    }
    float4 wv0 = *(const float4*)&gwinv[base];
    float4 wv1 = *(const float4*)&gwinv[base + 4];
    float wl[8] = {wv0.x, wv0.y, wv0.z, wv0.w, wv1.x, wv1.y, wv1.z, wv1.w};
    __syncthreads();

    int wvid = tid >> 6, lane = tid & 63;
    const int4* pe4 = (const int4*)pedges;

    while (true) {
        // ---- phase A: pushers -> P += 0.5r, pamt = r*winv, mark group ----
        {
            f32x4 r0 = *(f32x4*)&R[base], r1 = *(f32x4*)&R[base + 4];
            f32x4 pa0, pa1;
            bool any = false;
#pragma unroll
            for (int u = 0; u < 4; ++u) {
                bool ps = (r0[u] >= RMAXF);
                any |= ps;
                pa0[u] = ps ? r0[u] * wl[u] : 0.0f;
                if (ps) P[base + u] += 0.5f * r0[u];
                bool ps2 = (r1[u] >= RMAXF);
                any |= ps2;
                pa1[u] = ps2 ? r1[u] * wl[4 + u] : 0.0f;
                if (ps2) P[base + 4 + u] += 0.5f * r1[u];
            }
            *(f32x4*)&pamt[base] = pa0;
            *(f32x4*)&pamt[base + 4] = pa1;
            if (any) groupAct[tid >> 3] = 1;  // same-value plain store, benign
        }
        __syncthreads();  // B1

        // ---- phase C: coalesced edge sweep over chunks with active sources ----
        for (int it = 0; it < 32; ++it) {
            int c = wvid * 32 + it;
            int glo = chunkLo[c], ghi = chunkHi[c];
            bool act = false;
            for (int g = glo; g <= ghi; ++g) act |= (groupAct[g] != 0);  // broadcast reads
            if (act) {
                int4 p4 = pe4[c * 64 + lane];  // 4 packed edges, 1KB/wave-instr, L2-hot
                int pk;
                float a;
                pk = p4.x; a = pamt[pk >> 11]; if (a != 0.f) atomicAdd(&D[pk & 2047], a);
                pk = p4.y; a = pamt[pk >> 11]; if (a != 0.f) atomicAdd(&D[pk & 2047], a);
                pk = p4.z; a = pamt[pk >> 11]; if (a != 0.f) atomicAdd(&D[pk & 2047], a);
                pk = p4.w; a = pamt[pk >> 11]; if (a != 0.f) atomicAdd(&D[pk & 2047], a);
            }
        }
        __syncthreads();  // B2

        if (tid < 32) groupAct[tid] = 0;
        if (tid == 0) sflag = 0;
        __syncthreads();  // B3

        // ---- phase E: R = R - push + D; D = 0; next-round flag ----
        {
            bool above = false;
#pragma unroll
            for (int l = 0; l < 8; l += 4) {
                int j = base + l;
                f32x4 r4 = *(f32x4*)&R[j];
                f32x4 d4 = *(f32x4*)&D[j];
                f32x4 rn;
#pragma unroll
                for (int u = 0; u < 4; ++u) {
                    float r = r4[u];
                    float push = (r >= RMAXF) ? r : 0.0f;
                    float v = (r - push) + d4[u];
                    rn[u] = v;
                    above |= (v >= RMAXF);
                }
                *(f32x4*)&R[j] = rn;
                *(f32x4*)&D[j] = z4;
            }
            if (above) sflag = 1;  // same-value plain store, benign
        }
        __syncthreads();  // B4
        if (sflag == 0) break;  // final round had no pushers -> exact no-op, converged
    }

    // ---- top-20 of P (lowest-index tie-break, matches lax.top_k) — R5-proven form ----
    float* cv = (float*)D;  // D is all zeros / dead; reuse
    int* ci = (int*)(D + 256);
    for (int s = 0; s < TOPK; ++s) {
        float bv = -1.0f;
        int bi = 0;
#pragma unroll
        for (int l = 0; l < 8; ++l) {
            float v = P[base + l];
            if (v > bv) { bv = v; bi = base + l; }  // strict > keeps lowest index
        }
        cv[tid] = bv;
        ci[tid] = bi;
        __syncthreads();
        for (int st = 128; st > 0; st >>= 1) {
            if (tid < st) {
                float ov = cv[tid + st];
                int oi = ci[tid + st];
                if (ov > cv[tid] || (ov == cv[tid] && oi < ci[tid])) { cv[tid] = ov; ci[tid] = oi; }
            }
            __syncthreads();
        }
        if (tid == 0) {
            tkv[row * TOPK + s] = cv[0];
            tki[row * TOPK + s] = ci[0];
            P[ci[0]] = -1.0f;  // P >= 0, safe sentinel
        }
        __syncthreads();
    }
}

// ---------------- out[row] = sum_v w_v * feats[idx_v] ----------------
__global__ __launch_bounds__(256) void final_kernel(const float* __restrict__ feats, const float* __restrict__ tkv,
                                                    const int* __restrict__ tki, float* __restrict__ out) {
    __shared__ float wv[TOPK];
    __shared__ int wi[TOPK];
    int row = blockIdx.x, tid = threadIdx.x;
    if (tid < TOPK) {
        wv[tid] = tkv[row * TOPK + tid];
        wi[tid] = tki[row * TOPK + tid];
    }
    __syncthreads();
    int c0 = tid * 8;
    float4 a0 = {0, 0, 0, 0}, a1 = {0, 0, 0, 0};
    for (int v = 0; v < TOPK; ++v) {
        float w = wv[v];
        int id = wi[v];
        const float4* fr = (const float4*)&feats[(size_t)id * DF + c0];
        float4 g0 = fr[0], g1 = fr[1];
        a0.x += w * g0.x; a0.y += w * g0.y; a0.z += w * g0.z; a0.w += w * g0.w;
        a1.x += w * g1.x; a1.y += w * g1.y; a1.z += w * g1.z; a1.w += w * g1.w;
    }
    float4* op = (float4*)&out[(size_t)row * DF + c0];
    op[0] = a0;
    op[1] = a1;
}

extern "C" void kernel_launch(void* const* d_in, const int* in_sizes, int n_in,
                              void* d_out, int out_size, void* d_ws, size_t ws_size,
                              hipStream_t stream) {
    const float* feats = (const float*)d_in[0];
    const int* ei = (const int*)d_in[1];
    float* out = (float*)d_out;

    // layout (int units); pedges first for 16B alignment of int4 loads
    int* pedges = (int*)d_ws;                  // [0, 32768)
    int* counts = pedges + NE;                 // [32768, 34816)
    int* cursor = counts + NN;                 // [34816, 36864)
    int* rowptr = cursor + NN;                 // [36864, 38913) +pad
    float* winv05 = (float*)(rowptr + NN + 4); // 38916 (16B-aligned)
    float* tkv = winv05 + NN;                  // 40964
    int* tki = (int*)(tkv + NN * TOPK);

    zero_kernel<<<(NN + 255) / 256, 256, 0, stream>>>(counts, cursor);
    count_kernel<<<(NE + 255) / 256, 256, 0, stream>>>(ei, counts);
    scan_kernel<<<1, 256, 0, stream>>>(counts, rowptr, winv05);
    fill_kernel<<<(NE + 255) / 256, 256, 0, stream>>>(ei, rowptr, cursor, pedges);
    push_topk_kernel<<<NN, 256, 0, stream>>>(pedges, winv05, tkv, tki);
    final_kernel<<<NN, 256, 0, stream>>>(feats, tkv, tki, out);
}

// Round 8
// 1715.155 us; speedup vs baseline: 1.1515x; 1.1515x over previous
//
#include <hip/hip_runtime.h>

#define NN 2048
#define NE 32768
#define DF 2048
#define TOPK 20
#define RMAXF 1e-5f

typedef __attribute__((ext_vector_type(4))) float f32x4;

// ---------------- zero counts/cursor ----------------
__global__ __launch_bounds__(256) void zero_kernel(int* __restrict__ counts, int* __restrict__ cursor) {
    int idx = blockIdx.x * 256 + threadIdx.x;
    if (idx < NN) { counts[idx] = 0; cursor[idx] = 0; }
}

// ---------------- per-row edge counts (duplicates kept) ----------------
__global__ __launch_bounds__(256) void count_kernel(const int* __restrict__ ei, int* __restrict__ counts) {
    int e = blockIdx.x * 256 + threadIdx.x;
    if (e < NE) atomicAdd(&counts[ei[e]], 1);
}

// ---------------- exclusive scan -> rowptr; winv05 = 0.5/deg ----------------
__global__ __launch_bounds__(256) void scan_kernel(const int* __restrict__ counts, int* __restrict__ rowptr,
                                                   float* __restrict__ winv05) {
    __shared__ int part[256];
    int tid = threadIdx.x;
    int base = tid * 8;
    int loc[8];
    int s = 0;
#pragma unroll
    for (int l = 0; l < 8; ++l) { loc[l] = s; s += counts[base + l]; }
    part[tid] = s;
    __syncthreads();
    for (int off = 1; off < 256; off <<= 1) {
        int v = (tid >= off) ? part[tid - off] : 0;
        __syncthreads();
        part[tid] += v;
        __syncthreads();
    }
    int excl = part[tid] - s;
#pragma unroll
    for (int l = 0; l < 8; ++l) {
        rowptr[base + l] = excl + loc[l];
        int c = counts[base + l];
        winv05[base + l] = c ? 0.5f / (float)c : 0.0f;
    }
    if (tid == 255) rowptr[NN] = excl + s;
}

// ---------------- fill packed CSR edges: pedges[k] = (src<<11)|dst (src ascending) ----------------
__global__ __launch_bounds__(256) void fill_kernel(const int* __restrict__ ei, const int* __restrict__ rowptr,
                                                   int* __restrict__ cursor, int* __restrict__ pedges) {
    int e = blockIdx.x * 256 + threadIdx.x;
    if (e < NE) {
        int r = ei[e];
        int c = ei[NE + e];
        int pos = atomicAdd(&cursor[r], 1);
        pedges[rowptr[r] + pos] = (r << 11) | c;
    }
}

// ---------------- per-source-row local push + top-20 ----------------
// R7's proven 4-barrier protocol; owner-private R/P/winv moved to registers,
// chunk activity via one LDS read + ballots, top-k via wave-0 shuffles.
__global__ __launch_bounds__(256) void push_topk_kernel(const int* __restrict__ pedges,
                                                        const float* __restrict__ gwinv,
                                                        float* __restrict__ tkv, int* __restrict__ tki) {
    __shared__ float D[NN];      // scatter target (atomics), zeroed each round by owners
    __shared__ float pamt[NN];   // per-source scatter amount this round; reused for P dump at end
    __shared__ int groupAct[32]; // 1 if any source in group of 64 pushes this round
    __shared__ int sflag;

    int tid = threadIdx.x, row = blockIdx.x;
    int base = tid * 8;
    int wvid = tid >> 6, lane = tid & 63;
    const f32x4 z4 = (f32x4){0.f, 0.f, 0.f, 0.f};

    *(f32x4*)&D[base] = z4;
    *(f32x4*)&D[base + 4] = z4;
    if (tid < 32) groupAct[tid] = 0;
    if (tid == 0) sflag = 0;

    // owner-private state in registers
    float R[8], P[8], wl[8];
    {
        float4 w0 = *(const float4*)&gwinv[base];
        float4 w1 = *(const float4*)&gwinv[base + 4];
        wl[0] = w0.x; wl[1] = w0.y; wl[2] = w0.z; wl[3] = w0.w;
        wl[4] = w1.x; wl[5] = w1.y; wl[6] = w1.z; wl[7] = w1.w;
    }
#pragma unroll
    for (int l = 0; l < 8; ++l) {
        R[l] = (base + l == row) ? 1.0f : 0.0f;  // R = e_row
        P[l] = 0.0f;
    }

    // chunk c covers edges [c*256, c*256+256); CSR order -> sources ascending.
    // lane<32 of wave w owns chunk w*32+lane; its source-group span as a 32-bit mask.
    unsigned myGroupMask = 0u;
    if (lane < 32) {
        int c = wvid * 32 + lane;
        int lo = pedges[c * 256] >> 17;         // src>>6
        int hi = pedges[c * 256 + 255] >> 17;
        unsigned him = (hi >= 31) ? 0xFFFFFFFFu : ((1u << (hi + 1)) - 1u);
        myGroupMask = him & ~((1u << lo) - 1u);
    }
    const int4* pe4 = (const int4*)pedges;
    int wbase = wvid * 2048 + lane;
    __syncthreads();  // init visible before round 1

    while (true) {
        // ---- phase A: pushers -> P += 0.5r (reg), pamt = r*winv (LDS), mark group ----
        bool any = false;
        f32x4 pa0, pa1;
#pragma unroll
        for (int u = 0; u < 4; ++u) {
            float r = R[u];
            bool ps = (r >= RMAXF);
            any |= ps;
            pa0[u] = ps ? r * wl[u] : 0.0f;
            if (ps) P[u] += 0.5f * r;
            float r2 = R[4 + u];
            bool ps2 = (r2 >= RMAXF);
            any |= ps2;
            pa1[u] = ps2 ? r2 * wl[4 + u] : 0.0f;
            if (ps2) P[4 + u] += 0.5f * r2;
        }
        *(f32x4*)&pamt[base] = pa0;
        *(f32x4*)&pamt[base + 4] = pa1;
        if (any) groupAct[tid >> 3] = 1;  // same-value plain store, benign
        __syncthreads();  // B1

        // ---- activity: 1 LDS read + 2 ballots ----
        bool gbit = (lane < 32) ? (groupAct[lane] != 0) : false;
        unsigned actBits = (unsigned)__ballot(gbit);
        bool act = (myGroupMask & actBits) != 0u;
        unsigned m = (unsigned)__ballot(act);

        if (m == 0xFFFFFFFFu) {
            // dense: straight-line sweep, loads pipeline 8-deep
#pragma unroll 8
            for (int c = 0; c < 32; ++c) {
                int4 p4 = pe4[wbase + c * 64];
                float a;
                a = pamt[p4.x >> 11]; if (a != 0.f) atomicAdd(&D[p4.x & 2047], a);
                a = pamt[p4.y >> 11]; if (a != 0.f) atomicAdd(&D[p4.y & 2047], a);
                a = pamt[p4.z >> 11]; if (a != 0.f) atomicAdd(&D[p4.z & 2047], a);
                a = pamt[p4.w >> 11]; if (a != 0.f) atomicAdd(&D[p4.w & 2047], a);
            }
        } else {
            while (m) {
                int c = __builtin_ctz(m);
                m &= m - 1;
                int4 p4 = pe4[wbase + c * 64];
                float a;
                a = pamt[p4.x >> 11]; if (a != 0.f) atomicAdd(&D[p4.x & 2047], a);
                a = pamt[p4.y >> 11]; if (a != 0.f) atomicAdd(&D[p4.y & 2047], a);
                a = pamt[p4.z >> 11]; if (a != 0.f) atomicAdd(&D[p4.z & 2047], a);
                a = pamt[p4.w >> 11]; if (a != 0.f) atomicAdd(&D[p4.w & 2047], a);
            }
        }
        __syncthreads();  // B2

        if (tid < 32) groupAct[tid] = 0;
        if (tid == 0) sflag = 0;
        __syncthreads();  // B3

        // ---- phase E: R = (pushed?0:R) + D (regs), D = 0, next-round flag ----
        f32x4 d0 = *(f32x4*)&D[base];
        f32x4 d1 = *(f32x4*)&D[base + 4];
        *(f32x4*)&D[base] = z4;
        *(f32x4*)&D[base + 4] = z4;
        bool above = false;
#pragma unroll
        for (int u = 0; u < 4; ++u) {
            float r = R[u];
            float rn = ((r >= RMAXF) ? 0.0f : r) + d0[u];
            R[u] = rn;
            above |= (rn >= RMAXF);
            float r2 = R[4 + u];
            float rn2 = ((r2 >= RMAXF) ? 0.0f : r2) + d1[u];
            R[4 + u] = rn2;
            above |= (rn2 >= RMAXF);
        }
        if (above) sflag = 1;  // same-value plain store, benign
        __syncthreads();  // B4
        if (sflag == 0) break;  // no entry >= RMAX anywhere -> converged
    }

    // ---- dump P regs to LDS (pamt is dead), then wave-0 register/shuffle top-20 ----
    *(f32x4*)&pamt[base] = (f32x4){P[0], P[1], P[2], P[3]};
    *(f32x4*)&pamt[base + 4] = (f32x4){P[4], P[5], P[6], P[7]};
    __syncthreads();
    if (tid < 64) {
        float pv[32];
#pragma unroll
        for (int i = 0; i < 8; ++i) {
            f32x4 v = *(f32x4*)&pamt[tid * 32 + i * 4];
            pv[i * 4 + 0] = v[0]; pv[i * 4 + 1] = v[1];
            pv[i * 4 + 2] = v[2]; pv[i * 4 + 3] = v[3];
        }
        for (int s = 0; s < TOPK; ++s) {
            float bv = -1.0f;
            int bi = 0;
#pragma unroll
            for (int j = 0; j < 32; ++j) {
                if (pv[j] > bv) { bv = pv[j]; bi = tid * 32 + j; }  // ascending j: lowest index kept
            }
#pragma unroll
            for (int off = 32; off >= 1; off >>= 1) {
                float ov = __shfl_xor(bv, off);
                int oi = __shfl_xor(bi, off);
                if (ov > bv || (ov == bv && oi < bi)) { bv = ov; bi = oi; }
            }
            if (tid == 0) {
                tkv[row * TOPK + s] = bv;  // P regs already carry the 0.5 factor
                tki[row * TOPK + s] = bi;
            }
            if ((bi >> 5) == tid) {
                int li = bi & 31;
#pragma unroll
                for (int j = 0; j < 32; ++j)
                    if (j == li) pv[j] = -1.0f;  // static unroll: no dynamic reg indexing
            }
        }
    }
}

// ---------------- out[row] = sum_v w_v * feats[idx_v] ----------------
__global__ __launch_bounds__(256) void final_kernel(const float* __restrict__ feats, const float* __restrict__ tkv,
                                                    const int* __restrict__ tki, float* __restrict__ out) {
    __shared__ float wv[TOPK];
    __shared__ int wi[TOPK];
    int row = blockIdx.x, tid = threadIdx.x;
    if (tid < TOPK) {
        wv[tid] = tkv[row * TOPK + tid];
        wi[tid] = tki[row * TOPK + tid];
    }
    __syncthreads();
    int c0 = tid * 8;
    float4 a0 = {0, 0, 0, 0}, a1 = {0, 0, 0, 0};
    for (int v = 0; v < TOPK; ++v) {
        float w = wv[v];
        int id = wi[v];
        const float4* fr = (const float4*)&feats[(size_t)id * DF + c0];
        float4 g0 = fr[0], g1 = fr[1];
        a0.x += w * g0.x; a0.y += w * g0.y; a0.z += w * g0.z; a0.w += w * g0.w;
        a1.x += w * g1.x; a1.y += w * g1.y; a1.z += w * g1.z; a1.w += w * g1.w;
    }
    float4* op = (float4*)&out[(size_t)row * DF + c0];
    op[0] = a0;
    op[1] = a1;
}

extern "C" void kernel_launch(void* const* d_in, const int* in_sizes, int n_in,
                              void* d_out, int out_size, void* d_ws, size_t ws_size,
                              hipStream_t stream) {
    const float* feats = (const float*)d_in[0];
    const int* ei = (const int*)d_in[1];
    float* out = (float*)d_out;

    // layout (int units); pedges first for 16B alignment of int4 loads
    int* pedges = (int*)d_ws;                  // [0, 32768)
    int* counts = pedges + NE;                 // [32768, 34816)
    int* cursor = counts + NN;                 // [34816, 36864)
    int* rowptr = cursor + NN;                 // [36864, 38913) +pad
    float* winv05 = (float*)(rowptr + NN + 4); // 38916 (16B-aligned)
    float* tkv = winv05 + NN;                  // 40964
    int* tki = (int*)(tkv + NN * TOPK);

    zero_kernel<<<(NN + 255) / 256, 256, 0, stream>>>(counts, cursor);
    count_kernel<<<(NE + 255) / 256, 256, 0, stream>>>(ei, counts);
    scan_kernel<<<1, 256, 0, stream>>>(counts, rowptr, winv05);
    fill_kernel<<<(NE + 255) / 256, 256, 0, stream>>>(ei, rowptr, cursor, pedges);
    push_topk_kernel<<<NN, 256, 0, stream>>>(pedges, winv05, tkv, tki);
    final_kernel<<<NN, 256, 0, stream>>>(feats, tkv, tki, out);
}

// Round 9
// 1702.216 us; speedup vs baseline: 1.1603x; 1.0076x over previous
//
#include <hip/hip_runtime.h>

#define NN 2048
#define NE 32768
#define DF 2048
#define TOPK 20
#define RMAXF 1e-5f
#define TCAP 64

typedef __attribute__((ext_vector_type(4))) float f32x4;
typedef __attribute__((ext_vector_type(8))) unsigned short u16x8;

// ---------------- zero counts/cursor ----------------
__global__ __launch_bounds__(256) void zero_kernel(int* __restrict__ counts, int* __restrict__ cursor) {
    int idx = blockIdx.x * 256 + threadIdx.x;
    if (idx < NN) { counts[idx] = 0; cursor[idx] = 0; }
}

// ---------------- per-row edge counts (duplicates kept) ----------------
__global__ __launch_bounds__(256) void count_kernel(const int* __restrict__ ei, int* __restrict__ counts) {
    int e = blockIdx.x * 256 + threadIdx.x;
    if (e < NE) atomicAdd(&counts[ei[e]], 1);
}

// ---------------- exclusive scan -> rowptr; winv05 = 0.5/deg ----------------
__global__ __launch_bounds__(256) void scan_kernel(const int* __restrict__ counts, int* __restrict__ rowptr,
                                                   float* __restrict__ winv05) {
    __shared__ int part[256];
    int tid = threadIdx.x;
    int base = tid * 8;
    int loc[8];
    int s = 0;
#pragma unroll
    for (int l = 0; l < 8; ++l) { loc[l] = s; s += counts[base + l]; }
    part[tid] = s;
    __syncthreads();
    for (int off = 1; off < 256; off <<= 1) {
        int v = (tid >= off) ? part[tid - off] : 0;
        __syncthreads();
        part[tid] += v;
        __syncthreads();
    }
    int excl = part[tid] - s;
#pragma unroll
    for (int l = 0; l < 8; ++l) {
        rowptr[base + l] = excl + loc[l];
        int c = counts[base + l];
        winv05[base + l] = c ? 0.5f / (float)c : 0.0f;
    }
    if (tid == 255) rowptr[NN] = excl + s;
}

// ---------------- fill CSR cols as ushort (src-grouped) ----------------
__global__ __launch_bounds__(256) void fill_kernel(const int* __restrict__ ei, const int* __restrict__ rowptr,
                                                   int* __restrict__ cursor, unsigned short* __restrict__ cols16) {
    int e = blockIdx.x * 256 + threadIdx.x;
    if (e < NE) {
        int r = ei[e];
        int c = ei[NE + e];
        int pos = atomicAdd(&cursor[r], 1);
        cols16[rowptr[r] + pos] = (unsigned short)c;
    }
}

// ---------------- per-source-row local push + top-20; edges LDS-resident ----------------
// Thread t owns sources [8t, 8t+8): R/P/winv/rowptr in registers. Push round:
// owners of entries >= RMAX walk THEIR OWN LDS-resident edge lists scattering
// amt = r*0.5/deg into D (LDS atomics). 2 barriers/round; convergence via
// __syncthreads_count. Rounds capped at TCAP (cap-48 passed in R1; monotone-safe).
__global__ __launch_bounds__(256) void push_topk_kernel(const unsigned short* __restrict__ gcols,
                                                        const int* __restrict__ rowptr_g,
                                                        const float* __restrict__ gwinv,
                                                        float* __restrict__ tkv, int* __restrict__ tki) {
    __shared__ __align__(16) unsigned short lcols[NE];  // 64 KB
    __shared__ float D[NN];                             // 8 KB scatter target

    int tid = threadIdx.x, row = blockIdx.x;
    int base = tid * 8;

    // stage edges global->LDS, coalesced ushort8
    const u16x8* gc8 = (const u16x8*)gcols;
#pragma unroll
    for (int i = 0; i < 16; ++i) {
        int ci = i * 256 + tid;
        *(u16x8*)&lcols[ci * 8] = gc8[ci];
    }
    const f32x4 z4 = (f32x4){0.f, 0.f, 0.f, 0.f};
    *(f32x4*)&D[base] = z4;
    *(f32x4*)&D[base + 4] = z4;

    float R[8], P[8], wl[8];
    int rp[9];
    {
        float4 w0 = *(const float4*)&gwinv[base];
        float4 w1 = *(const float4*)&gwinv[base + 4];
        wl[0] = w0.x; wl[1] = w0.y; wl[2] = w0.z; wl[3] = w0.w;
        wl[4] = w1.x; wl[5] = w1.y; wl[6] = w1.z; wl[7] = w1.w;
    }
#pragma unroll
    for (int i = 0; i < 9; ++i) rp[i] = rowptr_g[base + i];
#pragma unroll
    for (int l = 0; l < 8; ++l) {
        R[l] = (base + l == row) ? 1.0f : 0.0f;
        P[l] = 0.0f;
    }
    __syncthreads();  // edges + D visible

    for (int t = 0; t < TCAP; ++t) {
        // ---- phase A: owned pushers -> P += 0.5r, R=0, walk own edges ----
#pragma unroll
        for (int s = 0; s < 8; ++s) {
            float r = R[s];
            if (r >= RMAXF) {
                P[s] += 0.5f * r;
                R[s] = 0.0f;  // pushed mass leaves; D added below
                float amt = r * wl[s];
                int p = rp[s], e = rp[s + 1];
                for (; p + 4 <= e; p += 4) {
                    int d0 = lcols[p], d1 = lcols[p + 1], d2 = lcols[p + 2], d3 = lcols[p + 3];
                    atomicAdd(&D[d0], amt);
                    atomicAdd(&D[d1], amt);
                    atomicAdd(&D[d2], amt);
                    atomicAdd(&D[d3], amt);
                }
                for (; p < e; ++p) atomicAdd(&D[lcols[p]], amt);
            }
        }
        __syncthreads();  // scatter complete before consume

        // ---- phase E: R += D, D = 0, convergence vote ----
        f32x4 d0 = *(f32x4*)&D[base];
        f32x4 d1 = *(f32x4*)&D[base + 4];
        *(f32x4*)&D[base] = z4;
        *(f32x4*)&D[base + 4] = z4;
        bool above = false;
#pragma unroll
        for (int u = 0; u < 4; ++u) {
            float rn = R[u] + d0[u];
            R[u] = rn;
            above |= (rn >= RMAXF);
            float rn2 = R[4 + u] + d1[u];
            R[4 + u] = rn2;
            above |= (rn2 >= RMAXF);
        }
        if (__syncthreads_count(above ? 1 : 0) == 0) break;  // barrier + vote
    }

    // ---- dump P into D (dead, all zeros), wave-0 shuffle top-20 (R8-proven) ----
    *(f32x4*)&D[base] = (f32x4){P[0], P[1], P[2], P[3]};
    *(f32x4*)&D[base + 4] = (f32x4){P[4], P[5], P[6], P[7]};
    __syncthreads();
    if (tid < 64) {
        float pv[32];
#pragma unroll
        for (int i = 0; i < 8; ++i) {
            f32x4 v = *(f32x4*)&D[tid * 32 + i * 4];
            pv[i * 4 + 0] = v[0]; pv[i * 4 + 1] = v[1];
            pv[i * 4 + 2] = v[2]; pv[i * 4 + 3] = v[3];
        }
        for (int s = 0; s < TOPK; ++s) {
            float bv = -1.0f;
            int bi = 0;
#pragma unroll
            for (int j = 0; j < 32; ++j) {
                if (pv[j] > bv) { bv = pv[j]; bi = tid * 32 + j; }  // ascending j: lowest index kept
            }
#pragma unroll
            for (int off = 32; off >= 1; off >>= 1) {
                float ov = __shfl_xor(bv, off);
                int oi = __shfl_xor(bi, off);
                if (ov > bv || (ov == bv && oi < bi)) { bv = ov; bi = oi; }
            }
            if (tid == 0) {
                tkv[row * TOPK + s] = bv;  // P regs already carry the 0.5 factor
                tki[row * TOPK + s] = bi;
            }
            if ((bi >> 5) == tid) {
                int li = bi & 31;
#pragma unroll
                for (int j = 0; j < 32; ++j)
                    if (j == li) pv[j] = -1.0f;  // static unroll: no dynamic reg indexing
            }
        }
    }
}

// ---------------- out[row] = sum_v w_v * feats[idx_v] ----------------
__global__ __launch_bounds__(256) void final_kernel(const float* __restrict__ feats, const float* __restrict__ tkv,
                                                    const int* __restrict__ tki, float* __restrict__ out) {
    __shared__ float wv[TOPK];
    __shared__ int wi[TOPK];
    int row = blockIdx.x, tid = threadIdx.x;
    if (tid < TOPK) {
        wv[tid] = tkv[row * TOPK + tid];
        wi[tid] = tki[row * TOPK + tid];
    }
    __syncthreads();
    int c0 = tid * 8;
    float4 a0 = {0, 0, 0, 0}, a1 = {0, 0, 0, 0};
    for (int v = 0; v < TOPK; ++v) {
        float w = wv[v];
        int id = wi[v];
        const float4* fr = (const float4*)&feats[(size_t)id * DF + c0];
        float4 g0 = fr[0], g1 = fr[1];
        a0.x += w * g0.x; a0.y += w * g0.y; a0.z += w * g0.z; a0.w += w * g0.w;
        a1.x += w * g1.x; a1.y += w * g1.y; a1.z += w * g1.z; a1.w += w * g1.w;
    }
    float4* op = (float4*)&out[(size_t)row * DF + c0];
    op[0] = a0;
    op[1] = a1;
}

extern "C" void kernel_launch(void* const* d_in, const int* in_sizes, int n_in,
                              void* d_out, int out_size, void* d_ws, size_t ws_size,
                              hipStream_t stream) {
    const float* feats = (const float*)d_in[0];
    const int* ei = (const int*)d_in[1];
    float* out = (float*)d_out;

    // layout: cols16 first (16B-aligned for ushort8 loads)
    unsigned short* cols16 = (unsigned short*)d_ws;   // 64 KB
    int* counts = (int*)(cols16 + NE);                // 2048
    int* cursor = counts + NN;                        // 2048
    int* rowptr = cursor + NN;                        // 2049 (+pad)
    float* winv05 = (float*)(rowptr + NN + 4);        // 2048 (16B-aligned)
    float* tkv = winv05 + NN;
    int* tki = (int*)(tkv + NN * TOPK);

    zero_kernel<<<(NN + 255) / 256, 256, 0, stream>>>(counts, cursor);
    count_kernel<<<(NE + 255) / 256, 256, 0, stream>>>(ei, counts);
    scan_kernel<<<1, 256, 0, stream>>>(counts, rowptr, winv05);
    fill_kernel<<<(NE + 255) / 256, 256, 0, stream>>>(ei, rowptr, cursor, cols16);
    push_topk_kernel<<<NN, 256, 0, stream>>>(cols16, rowptr, winv05, tkv, tki);
    final_kernel<<<NN, 256, 0, stream>>>(feats, tkv, tki, out);
}